// Round 7
// baseline (10678.449 us; speedup 1.0000x reference)
//
#include <hip/hip_runtime.h>
#include <hip/hip_bf16.h>

typedef short bf16x8 __attribute__((ext_vector_type(8)));
typedef short bf16x16 __attribute__((ext_vector_type(16)));
typedef float f32x4 __attribute__((ext_vector_type(4)));
typedef __hip_bfloat16 bf16;
typedef unsigned long long ull;

#define NEGV -10000.0f

// Problem dims: B=64, T=256, E=300, H=500, K=64(tags), V=32000
// Padded: Ep=320, Hp=512, layer-1 input 2*Hp=1024, gate width 4096 = 2dir*4gate*512

__device__ __forceinline__ float sigm(float v) { return 1.0f / (1.0f + __expf(-v)); }
__device__ __forceinline__ float tanh_(float v) { float e = __expf(2.0f * v); return 1.0f - 2.0f / (e + 1.0f); }

// async global->LDS, 16B per lane, wave-uniform LDS base + lane*16
__device__ __forceinline__ void async_load16(const bf16* g, const char* l) {
  __builtin_amdgcn_global_load_lds((const __attribute__((address_space(1))) void*)g,
                                   (__attribute__((address_space(3))) void*)l, 16, 0, 0);
}

// ---------------- weight packing into MFMA fragment-linear layout ----------------
// B-frag layout: dst[((nt*Kt + kt)*64 + lane)*8 + u] = B[kt*32 + (lane>>4)*8 + u][nt*16 + (lane&15)]

__global__ __launch_bounds__(256) void pack_w0(const float* __restrict__ wf, const float* __restrict__ wb,
                                               bf16* __restrict__ dst) {
  int idx = blockIdx.x * 256 + threadIdx.x;            // 4096*320 = 1310720
  int u = idx & 7, lane = (idx >> 3) & 63, rem = idx >> 9;
  int kt = rem % 10, nt = rem / 10;
  int n = (nt << 4) + (lane & 15), k = (kt << 5) + ((lane >> 4) << 3) + u;
  int d = n >> 11, g = (n >> 9) & 3, j = n & 511;
  float v = 0.f;
  if (j < 500 && k < 300) v = (d ? wb : wf)[(g * 500 + j) * 300 + k];
  dst[idx] = __float2bfloat16(v);
}

__global__ __launch_bounds__(256) void pack_whh(const float* __restrict__ w, bf16* __restrict__ dst) {
  int idx = blockIdx.x * 256 + threadIdx.x;            // 2048*512 = 1048576
  int u = idx & 7, lane = (idx >> 3) & 63, rem = idx >> 9;
  int kt = rem & 15, nt = rem >> 4;
  int n = (nt << 4) + (lane & 15), k = (kt << 5) + ((lane >> 4) << 3) + u;
  int g = n >> 9, j = n & 511;
  float v = 0.f;
  if (j < 500 && k < 500) v = w[(g * 500 + j) * 500 + k];
  dst[idx] = __float2bfloat16(v);
}

__global__ __launch_bounds__(256) void pack_w1(const float* __restrict__ wf, const float* __restrict__ wb,
                                               bf16* __restrict__ dst) {
  int idx = blockIdx.x * 256 + threadIdx.x;            // 4096*1024 = 4194304
  int u = idx & 7, lane = (idx >> 3) & 63, rem = idx >> 9;
  int kt = rem & 31, nt = rem >> 5;
  int n = (nt << 4) + (lane & 15), k = (kt << 5) + ((lane >> 4) << 3) + u;
  int d = n >> 11, g = (n >> 9) & 3, j = n & 511;
  int kk = k & 511;
  int ks = (k < 512) ? kk : 500 + kk;
  float v = 0.f;
  if (j < 500 && kk < 500) v = (d ? wb : wf)[(g * 500 + j) * 1000 + ks];
  dst[idx] = __float2bfloat16(v);
}

__global__ __launch_bounds__(256) void pack_wout(const float* __restrict__ w, bf16* __restrict__ dst) {
  int idx = blockIdx.x * 256 + threadIdx.x;            // 4*32*512 = 65536
  int u = idx & 7, lane = (idx >> 3) & 63, rem = idx >> 9;
  int kt = rem & 31, nt = rem >> 5;
  int n = (nt << 4) + (lane & 15), k = (kt << 5) + ((lane >> 4) << 3) + u;
  int kk = k & 511;
  int ks = (k < 512) ? kk : 500 + kk;
  float v = 0.f;
  if (kk < 500) v = w[n * 1000 + ks];
  dst[idx] = __float2bfloat16(v);
}

__global__ __launch_bounds__(256) void pack_bias(const float* __restrict__ bf_, const float* __restrict__ bb_,
                                                 float* __restrict__ dst) {
  int idx = blockIdx.x * 256 + threadIdx.x;            // 4096
  int d = idx >> 11, g = (idx >> 9) & 3, j = idx & 511;
  dst[idx] = (j < 500) ? (d ? bb_ : bf_)[g * 500 + j] : 0.f;
}

// ---------------- embedding gather -> bf16 [T*B][320] ----------------
__global__ __launch_bounds__(256) void embed_k(const int* __restrict__ x, const float* __restrict__ em,
                                               bf16* __restrict__ xs) {
  int idx = blockIdx.x * 256 + threadIdx.x;            // 16384*320
  int e = idx % 320;
  int row = idx / 320;
  int t = row >> 6, b = row & 63;
  float v = 0.f;
  if (e < 300) {
    int xv = x[b * 256 + t];
    v = em[(size_t)xv * 300 + e];
  }
  xs[idx] = __float2bfloat16(v);
}

// ---------------- MFMA GEMM: preP = A[16384][Kdim] @ Bfrag, epilogue scatters into
// per-thread-contiguous lstm consumption layout:
// preP[(((t*2+dir)*32+jb)*4+gate)*1024 + lane*16 + (mt*4+r)]
__global__ __launch_bounds__(256) void gemm_nt(const bf16* __restrict__ A, const bf16* __restrict__ Bf,
                                               bf16* __restrict__ C, int Kdim, int Kt) {
  const int lane = threadIdx.x & 63, wave = threadIdx.x >> 6;
  const int lr = lane & 15, lh = lane >> 4;
  const int mb = blockIdx.x * 64;
  const int ntb = blockIdx.y * 16 + wave * 4;
  f32x4 acc[4][4] = {};
  for (int kt = 0; kt < Kt; ++kt) {
    bf16x8 a[4], b[4];
#pragma unroll
    for (int mt = 0; mt < 4; ++mt)
      a[mt] = *(const bf16x8*)(A + (size_t)(mb + mt * 16 + lr) * Kdim + kt * 32 + lh * 8);
#pragma unroll
    for (int q = 0; q < 4; ++q)
      b[q] = *(const bf16x8*)(Bf + ((size_t)(ntb + q) * Kt + kt) * 512 + lane * 8);
#pragma unroll
    for (int mt = 0; mt < 4; ++mt)
#pragma unroll
      for (int q = 0; q < 4; ++q)
        acc[mt][q] = __builtin_amdgcn_mfma_f32_16x16x32_bf16(a[mt], b[q], acc[mt][q], 0, 0, 0);
  }
  const int t = blockIdx.x;  // rows [mb, mb+64) are exactly timestep t
#pragma unroll
  for (int q = 0; q < 4; ++q) {
    const int colbase = (ntb + q) * 16;
    const int dirq = colbase >> 11, gq = (colbase >> 9) & 3, jbq = (colbase >> 4) & 31;
    unsigned short vals[16];
#pragma unroll
    for (int mt = 0; mt < 4; ++mt)
#pragma unroll
      for (int r = 0; r < 4; ++r) {
        bf16 hb = __float2bfloat16(acc[mt][q][r]);
        vals[mt * 4 + r] = *(unsigned short*)&hb;
      }
    bf16* outp = C + ((((size_t)t * 2 + dirq) * 32 + jbq) * 4 + gq) * 1024 + lane * 16;
    *(bf16x8*)(outp) = *(const bf16x8*)(vals);
    *(bf16x8*)(outp + 8) = *(const bf16x8*)(vals + 8);
  }
}

// ---------------- cooperative dual-direction LSTM layer ----------------
// grid(32 jb-tiles), 256 threads (wave = gate). Each block runs BOTH directions:
// per superstep s, phase F (t=s) then phase B (t=255-s). Each direction's flag RTT
// hides under the other direction's compute phase. Weights for both dirs live in
// LDS (128KB, staged once, lane-linear = conflict-free ds_read_b128, no remat risk).
// preP gives each thread its 16 gate pre-activations as ONE 32B load. h exchanged
// via sc0/sc1 write-through stores + plain cached loads (first-touch-after-write).
__global__ __launch_bounds__(256, 1) void lstm_dual(const bf16* __restrict__ preP, const bf16* __restrict__ whh,
                                                    const float* __restrict__ bias, bf16* __restrict__ hout,
                                                    unsigned int* __restrict__ flags) {
  const int tid = threadIdx.x, lane = tid & 63, wave = tid >> 6;
  const int lr = lane & 15, lh = lane >> 4;
  const int jb = blockIdx.x;
  unsigned int* flgF = flags;
  unsigned int* flgB = flags + 64;
  __shared__ __align__(16) char wlds[131072];  // [dir][gate][kt][lane*16B]
  __shared__ float xch[4 * 64 * 17];           // [gate][row][16 cols] pad 17

  // stage weights for both dirs, this jb slice: 8 segs x 16KB
#pragma unroll
  for (int seg = 0; seg < 8; ++seg) {
    const bf16* src = whh + (size_t)((seg >> 2) * 128 + (seg & 3) * 32 + jb) * 8192;
#pragma unroll
    for (int it = 0; it < 4; ++it)
      async_load16(src + it * 2048 + tid * 8, wlds + seg * 16384 + it * 4096 + tid * 16);
  }
  asm volatile("s_waitcnt vmcnt(0)" ::: "memory");
  __syncthreads();

  const float bbF = bias[wave * 512 + jb * 16 + lr];
  const float bbB = bias[2048 + wave * 512 + jb * 16 + lr];
  const int srow = tid >> 2, sq = tid & 3;  // cell mapping: row srow, cols sq*4..+3
  float csF[4] = {0.f, 0.f, 0.f, 0.f}, csB[4] = {0.f, 0.f, 0.f, 0.f};

  for (int s = 0; s < 256; ++s) {
    const int tF = s, tB = 255 - s;
    if (s > 0) {
      const unsigned int tgt = (unsigned int)s;
      for (;;) {
        unsigned int v = __hip_atomic_load(flgF + (lane & 31), __ATOMIC_RELAXED, __HIP_MEMORY_SCOPE_AGENT);
        if (__all((int)(v >= tgt))) break;
      }
      for (;;) {
        unsigned int v = __hip_atomic_load(flgB + (lane & 31), __ATOMIC_RELAXED, __HIP_MEMORY_SCOPE_AGENT);
        if (__all((int)(v >= tgt))) break;
      }
      asm volatile("" ::: "memory");
    }
    // ================= phase F =================
    {
      bf16x16 pp = *(const bf16x16*)(preP + ((((size_t)tF * 2 + 0) * 32 + jb) * 4 + wave) * 1024 + lane * 16);
      f32x4 acc[4] = {};
      if (s > 0) {
        const bf16* hp = hout + (size_t)(tF - 1) * 65536 + (size_t)lr * 1024 + lh * 8;
        const char* wl = wlds + (wave * 16) * 1024 + lane * 16;
#pragma unroll 4
        for (int kt = 0; kt < 16; ++kt) {
          bf16x8 wf = *(const bf16x8*)(wl + kt * 1024);
#pragma unroll
          for (int mt = 0; mt < 4; ++mt) {
            bf16x8 af = *(const bf16x8*)(hp + mt * 16384 + kt * 32);
            acc[mt] = __builtin_amdgcn_mfma_f32_16x16x32_bf16(af, wf, acc[mt], 0, 0, 0);
          }
        }
      }
#pragma unroll
      for (int mt = 0; mt < 4; ++mt)
#pragma unroll
        for (int r = 0; r < 4; ++r) {
          bf16 pv; *(unsigned short*)&pv = (unsigned short)pp[mt * 4 + r];
          xch[(wave * 64 + mt * 16 + lh * 4 + r) * 17 + lr] = acc[mt][r] + bbF + __bfloat162float(pv);
        }
    }
    __syncthreads();
    {
      ull pk = 0;
#pragma unroll
      for (int i = 0; i < 4; ++i) {
        int col = sq * 4 + i;
        float gi = xch[(0 * 64 + srow) * 17 + col];
        float gf = xch[(1 * 64 + srow) * 17 + col];
        float gg = xch[(2 * 64 + srow) * 17 + col];
        float go = xch[(3 * 64 + srow) * 17 + col];
        float cn = sigm(gf) * csF[i] + sigm(gi) * tanh_(gg);
        csF[i] = cn;
        bf16 hb = __float2bfloat16(sigm(go) * tanh_(cn));
        pk |= (ull)(*(unsigned short*)&hb) << (16 * i);
      }
      ull* hq = (ull*)(hout + ((size_t)tF * 64 + srow) * 1024 + jb * 16 + sq * 4);
      __hip_atomic_store(hq, pk, __ATOMIC_RELAXED, __HIP_MEMORY_SCOPE_AGENT);
    }
    asm volatile("s_waitcnt vmcnt(0)" ::: "memory");
    __syncthreads();
    if (tid == 0)
      __hip_atomic_store(flgF + jb, (unsigned int)(s + 1), __ATOMIC_RELAXED, __HIP_MEMORY_SCOPE_AGENT);
    // ================= phase B =================
    {
      bf16x16 pp = *(const bf16x16*)(preP + ((((size_t)tB * 2 + 1) * 32 + jb) * 4 + wave) * 1024 + lane * 16);
      f32x4 acc[4] = {};
      if (s > 0) {
        const bf16* hp = hout + (size_t)(tB + 1) * 65536 + 512 + (size_t)lr * 1024 + lh * 8;
        const char* wl = wlds + ((4 + wave) * 16) * 1024 + lane * 16;
#pragma unroll 4
        for (int kt = 0; kt < 16; ++kt) {
          bf16x8 wf = *(const bf16x8*)(wl + kt * 1024);
#pragma unroll
          for (int mt = 0; mt < 4; ++mt) {
            bf16x8 af = *(const bf16x8*)(hp + mt * 16384 + kt * 32);
            acc[mt] = __builtin_amdgcn_mfma_f32_16x16x32_bf16(af, wf, acc[mt], 0, 0, 0);
          }
        }
      }
#pragma unroll
      for (int mt = 0; mt < 4; ++mt)
#pragma unroll
        for (int r = 0; r < 4; ++r) {
          bf16 pv; *(unsigned short*)&pv = (unsigned short)pp[mt * 4 + r];
          xch[(wave * 64 + mt * 16 + lh * 4 + r) * 17 + lr] = acc[mt][r] + bbB + __bfloat162float(pv);
        }
    }
    __syncthreads();
    {
      ull pk = 0;
#pragma unroll
      for (int i = 0; i < 4; ++i) {
        int col = sq * 4 + i;
        float gi = xch[(0 * 64 + srow) * 17 + col];
        float gf = xch[(1 * 64 + srow) * 17 + col];
        float gg = xch[(2 * 64 + srow) * 17 + col];
        float go = xch[(3 * 64 + srow) * 17 + col];
        float cn = sigm(gf) * csB[i] + sigm(gi) * tanh_(gg);
        csB[i] = cn;
        bf16 hb = __float2bfloat16(sigm(go) * tanh_(cn));
        pk |= (ull)(*(unsigned short*)&hb) << (16 * i);
      }
      ull* hq = (ull*)(hout + ((size_t)tB * 64 + srow) * 1024 + 512 + jb * 16 + sq * 4);
      __hip_atomic_store(hq, pk, __ATOMIC_RELAXED, __HIP_MEMORY_SCOPE_AGENT);
    }
    asm volatile("s_waitcnt vmcnt(0)" ::: "memory");
    __syncthreads();
    if (tid == 0)
      __hip_atomic_store(flgB + jb, (unsigned int)(s + 1), __ATOMIC_RELAXED, __HIP_MEMORY_SCOPE_AGENT);
  }
}

// ---------------- emit projection: emit[16384][64] = h1 @ WoutB + bout, masked ----------------
__global__ __launch_bounds__(256) void emit_k(const bf16* __restrict__ h1, const bf16* __restrict__ wo,
                                              const float* __restrict__ bout, const int* __restrict__ x,
                                              float* __restrict__ emit) {
  const int tid = threadIdx.x, lane = tid & 63, wave = tid >> 6;
  const int lr = lane & 15, lh = lane >> 4;
  const int mb = blockIdx.x * 64 + wave * 16;
  f32x4 acc[4] = {};
  for (int kt = 0; kt < 32; ++kt) {
    bf16x8 a = *(const bf16x8*)(h1 + (size_t)(mb + lr) * 1024 + kt * 32 + lh * 8);
#pragma unroll
    for (int q = 0; q < 4; ++q) {
      bf16x8 b = *(const bf16x8*)(wo + ((size_t)(q * 32 + kt) * 64 + lane) * 8);
      acc[q] = __builtin_amdgcn_mfma_f32_16x16x32_bf16(a, b, acc[q], 0, 0, 0);
    }
  }
#pragma unroll
  for (int q = 0; q < 4; ++q)
#pragma unroll
    for (int r = 0; r < 4; ++r) {
      int row = mb + lh * 4 + r;
      int col = q * 16 + lr;
      int tt = row >> 6, bi = row & 63;
      float m = (x[bi * 256 + tt] > 0) ? 1.f : 0.f;
      emit[(size_t)row * 64 + col] = (acc[q][r] + bout[col]) * m;
    }
}

// ---------------- CRF forward + gold score, one block per batch element ----------------
__global__ __launch_bounds__(256) void crf_k(const float* __restrict__ emit, const float* __restrict__ trans,
                                             const int* __restrict__ x, const int* __restrict__ y0,
                                             float* __restrict__ out) {
  const int b = blockIdx.x, tid = threadIdx.x;
  __shared__ float tr[4096];
  __shared__ float sc[2][64];
  __shared__ float pm[4][64], ps[4][64];
  __shared__ float redw[4];
  for (int i = tid; i < 4096; i += 256) tr[i] = trans[i];
  if (tid < 64) sc[0][tid] = (tid == 2) ? 0.f : NEGV;  // SOS=2
  __syncthreads();
  {
    const int t = tid;
    const int tag = y0[b * 256 + t];
    const int prev = t ? y0[b * 256 + t - 1] : 2;
    const float m = (x[b * 256 + t] > 0) ? 1.f : 0.f;
    float g = emit[((size_t)t * 64 + b) * 64 + tag] + tr[tag * 64 + prev] * m;
    for (int o = 32; o; o >>= 1) g += __shfl_down(g, o, 64);
    if ((tid & 63) == 0) redw[tid >> 6] = g;
  }
  __syncthreads();
  const float gold = redw[0] + redw[1] + redw[2] + redw[3];
  const int j = tid & 63, kq = tid >> 6;
  int cur = 0;
  for (int t = 0; t < 256; ++t) {
    const float* trj = tr + j * 64 + kq * 16;
    const float* scc = sc[cur] + kq * 16;
    float v[16];
    float mx = -3.0e38f;
#pragma unroll
    for (int k = 0; k < 16; ++k) {
      v[k] = scc[k] + trj[k];
      mx = fmaxf(mx, v[k]);
    }
    float sm = 0.f;
#pragma unroll
    for (int k = 0; k < 16; ++k) sm += __expf(v[k] - mx);
    pm[kq][j] = mx;
    ps[kq][j] = sm;
    __syncthreads();
    if (kq == 0) {
      float M = fmaxf(fmaxf(pm[0][j], pm[1][j]), fmaxf(pm[2][j], pm[3][j]));
      float S = ps[0][j] * __expf(pm[0][j] - M) + ps[1][j] * __expf(pm[1][j] - M) +
                ps[2][j] * __expf(pm[2][j] - M) + ps[3][j] * __expf(pm[3][j] - M);
      float nv = M + __logf(S) + emit[((size_t)t * 64 + b) * 64 + j];
      sc[cur ^ 1][j] = (x[b * 256 + t] > 0) ? nv : sc[cur][j];
    }
    __syncthreads();
    cur ^= 1;
  }
  if (tid < 64) {
    float v2 = sc[cur][tid];
    float M = v2;
    for (int o = 32; o; o >>= 1) M = fmaxf(M, __shfl_xor(M, o, 64));
    float s2 = __expf(v2 - M);
    for (int o = 32; o; o >>= 1) s2 += __shfl_xor(s2, o, 64);
    if (tid == 0) out[b] = M + __logf(s2) - gold;
  }
}

// ---------------- launch ----------------
extern "C" void kernel_launch(void* const* d_in, const int* in_sizes, int n_in, void* d_out, int out_size,
                              void* d_ws, size_t ws_size, hipStream_t stream) {
  (void)in_sizes; (void)n_in; (void)out_size; (void)ws_size;
  const int* x = (const int*)d_in[0];
  const int* y0 = (const int*)d_in[1];
  const float* embed = (const float*)d_in[2];
  const float* Wih0f = (const float*)d_in[3];
  const float* Whh0f = (const float*)d_in[4];
  const float* b0f = (const float*)d_in[5];
  const float* Wih0b = (const float*)d_in[6];
  const float* Whh0b = (const float*)d_in[7];
  const float* b0b = (const float*)d_in[8];
  const float* Wih1f = (const float*)d_in[9];
  const float* Whh1f = (const float*)d_in[10];
  const float* b1f = (const float*)d_in[11];
  const float* Wih1b = (const float*)d_in[12];
  const float* Whh1b = (const float*)d_in[13];
  const float* b1b = (const float*)d_in[14];
  const float* Wout = (const float*)d_in[15];
  const float* bout = (const float*)d_in[16];
  const float* trans = (const float*)d_in[17];

  char* p = (char*)d_ws;
  auto take = [&](size_t n) { char* r = p; p += (n + 255) & ~(size_t)255; return r; };
  unsigned int* flags = (unsigned int*)take(2048 * sizeof(unsigned int));  // [layer][F/B slots]
  bf16* xs = (bf16*)take(16384ull * 320 * 2);
  bf16* preP = (bf16*)take(16384ull * 4096 * 2);
  bf16* h0 = (bf16*)take(16384ull * 1024 * 2);
  bf16* h1 = (bf16*)take(16384ull * 1024 * 2);
  float* emitb = (float*)take(16384ull * 64 * 4);
  bf16* W0B = (bf16*)take(4096ull * 320 * 2);
  bf16* W1B = (bf16*)take(4096ull * 1024 * 2);
  bf16* WhhB = (bf16*)take(4ull * 1048576 * 2);
  bf16* WoB = (bf16*)take(64ull * 1024 * 2);
  float* bias0 = (float*)take(4096 * 4);
  float* bias1 = (float*)take(4096 * 4);

  hipMemsetAsync(flags, 0, 2048 * sizeof(unsigned int), stream);
  hipLaunchKernelGGL(pack_w0, dim3(5120), dim3(256), 0, stream, Wih0f, Wih0b, W0B);
  hipLaunchKernelGGL(pack_whh, dim3(4096), dim3(256), 0, stream, Whh0f, WhhB + 0ull * 1048576);
  hipLaunchKernelGGL(pack_whh, dim3(4096), dim3(256), 0, stream, Whh0b, WhhB + 1ull * 1048576);
  hipLaunchKernelGGL(pack_whh, dim3(4096), dim3(256), 0, stream, Whh1f, WhhB + 2ull * 1048576);
  hipLaunchKernelGGL(pack_whh, dim3(4096), dim3(256), 0, stream, Whh1b, WhhB + 3ull * 1048576);
  hipLaunchKernelGGL(pack_w1, dim3(16384), dim3(256), 0, stream, Wih1f, Wih1b, W1B);
  hipLaunchKernelGGL(pack_wout, dim3(256), dim3(256), 0, stream, Wout, WoB);
  hipLaunchKernelGGL(pack_bias, dim3(16), dim3(256), 0, stream, b0f, b0b, bias0);
  hipLaunchKernelGGL(pack_bias, dim3(16), dim3(256), 0, stream, b1f, b1b, bias1);
  hipLaunchKernelGGL(embed_k, dim3(20480), dim3(256), 0, stream, x, embed, xs);

  hipLaunchKernelGGL(gemm_nt, dim3(256, 16), dim3(256), 0, stream, xs, W0B, preP, 320, 10);
  {
    const bf16* a0 = preP; const bf16* a1 = WhhB; const float* a2 = bias0; bf16* a3 = h0;
    unsigned int* a4 = flags;  // layer0 flag region
    void* args[] = {&a0, &a1, &a2, &a3, &a4};
    hipLaunchCooperativeKernel((void*)lstm_dual, dim3(32), dim3(256), args, 0, stream);
  }
  hipLaunchKernelGGL(gemm_nt, dim3(256, 16), dim3(256), 0, stream, h0, W1B, preP, 1024, 32);
  {
    const bf16* a0 = preP; const bf16* a1 = WhhB + 2ull * 1048576; const float* a2 = bias1; bf16* a3 = h1;
    unsigned int* a4 = flags + 1024;  // layer1 flag region
    void* args[] = {&a0, &a1, &a2, &a3, &a4};
    hipLaunchCooperativeKernel((void*)lstm_dual, dim3(32), dim3(256), args, 0, stream);
  }
  hipLaunchKernelGGL(emit_k, dim3(256), dim3(256), 0, stream, h1, WoB, bout, x, emitb);
  hipLaunchKernelGGL(crf_k, dim3(64), dim3(256), 0, stream, emitb, trans, x, y0, (float*)d_out);
}

// Round 8
// 9284.615 us; speedup vs baseline: 1.1501x; 1.1501x over previous
//
#include <hip/hip_runtime.h>
#include <hip/hip_bf16.h>

typedef short bf16x8 __attribute__((ext_vector_type(8)));
typedef short bf16x16 __attribute__((ext_vector_type(16)));
typedef float f32x4 __attribute__((ext_vector_type(4)));
typedef __hip_bfloat16 bf16;
typedef unsigned long long ull;

#define NEGV -10000.0f

// Problem dims: B=64, T=256, E=300, H=500, K=64(tags), V=32000
// Padded: Ep=320, Hp=512, layer-1 input 2*Hp=1024, gate width 4096 = 2dir*4gate*512

__device__ __forceinline__ float sigm(float v) { return 1.0f / (1.0f + __expf(-v)); }
__device__ __forceinline__ float tanh_(float v) { float e = __expf(2.0f * v); return 1.0f - 2.0f / (e + 1.0f); }

// ---------------- weight packing into MFMA fragment-linear layout ----------------
// B-frag layout: dst[((nt*Kt + kt)*64 + lane)*8 + u] = B[kt*32 + (lane>>4)*8 + u][nt*16 + (lane&15)]

__global__ __launch_bounds__(256) void pack_w0(const float* __restrict__ wf, const float* __restrict__ wb,
                                               bf16* __restrict__ dst) {
  int idx = blockIdx.x * 256 + threadIdx.x;            // 4096*320 = 1310720
  int u = idx & 7, lane = (idx >> 3) & 63, rem = idx >> 9;
  int kt = rem % 10, nt = rem / 10;
  int n = (nt << 4) + (lane & 15), k = (kt << 5) + ((lane >> 4) << 3) + u;
  int d = n >> 11, g = (n >> 9) & 3, j = n & 511;
  float v = 0.f;
  if (j < 500 && k < 300) v = (d ? wb : wf)[(g * 500 + j) * 300 + k];
  dst[idx] = __float2bfloat16(v);
}

__global__ __launch_bounds__(256) void pack_whh(const float* __restrict__ w, bf16* __restrict__ dst) {
  int idx = blockIdx.x * 256 + threadIdx.x;            // 2048*512 = 1048576
  int u = idx & 7, lane = (idx >> 3) & 63, rem = idx >> 9;
  int kt = rem & 15, nt = rem >> 4;
  int n = (nt << 4) + (lane & 15), k = (kt << 5) + ((lane >> 4) << 3) + u;
  int g = n >> 9, j = n & 511;
  float v = 0.f;
  if (j < 500 && k < 500) v = w[(g * 500 + j) * 500 + k];
  dst[idx] = __float2bfloat16(v);
}

__global__ __launch_bounds__(256) void pack_w1(const float* __restrict__ wf, const float* __restrict__ wb,
                                               bf16* __restrict__ dst) {
  int idx = blockIdx.x * 256 + threadIdx.x;            // 4096*1024 = 4194304
  int u = idx & 7, lane = (idx >> 3) & 63, rem = idx >> 9;
  int kt = rem & 31, nt = rem >> 5;
  int n = (nt << 4) + (lane & 15), k = (kt << 5) + ((lane >> 4) << 3) + u;
  int d = n >> 11, g = (n >> 9) & 3, j = n & 511;
  int kk = k & 511;
  int ks = (k < 512) ? kk : 500 + kk;
  float v = 0.f;
  if (j < 500 && kk < 500) v = (d ? wb : wf)[(g * 500 + j) * 1000 + ks];
  dst[idx] = __float2bfloat16(v);
}

__global__ __launch_bounds__(256) void pack_wout(const float* __restrict__ w, bf16* __restrict__ dst) {
  int idx = blockIdx.x * 256 + threadIdx.x;            // 4*32*512 = 65536
  int u = idx & 7, lane = (idx >> 3) & 63, rem = idx >> 9;
  int kt = rem & 31, nt = rem >> 5;
  int n = (nt << 4) + (lane & 15), k = (kt << 5) + ((lane >> 4) << 3) + u;
  int kk = k & 511;
  int ks = (k < 512) ? kk : 500 + kk;
  float v = 0.f;
  if (kk < 500) v = w[n * 1000 + ks];
  dst[idx] = __float2bfloat16(v);
}

__global__ __launch_bounds__(256) void pack_bias(const float* __restrict__ bf_, const float* __restrict__ bb_,
                                                 float* __restrict__ dst) {
  int idx = blockIdx.x * 256 + threadIdx.x;            // 4096
  int d = idx >> 11, g = (idx >> 9) & 3, j = idx & 511;
  dst[idx] = (j < 500) ? (d ? bb_ : bf_)[g * 500 + j] : 0.f;
}

// ---------------- embedding gather -> bf16 [T*B][320] ----------------
__global__ __launch_bounds__(256) void embed_k(const int* __restrict__ x, const float* __restrict__ em,
                                               bf16* __restrict__ xs) {
  int idx = blockIdx.x * 256 + threadIdx.x;            // 16384*320
  int e = idx % 320;
  int row = idx / 320;
  int t = row >> 6, b = row & 63;
  float v = 0.f;
  if (e < 300) {
    int xv = x[b * 256 + t];
    v = em[(size_t)xv * 300 + e];
  }
  xs[idx] = __float2bfloat16(v);
}

// ---------------- MFMA GEMM: preP = A[16384][Kdim] @ Bfrag, epilogue scatters into
// per-thread-contiguous lstm consumption layout:
// preP[(((t*2+dir)*32+jb)*4+gate)*1024 + lane*16 + (mt*4+r)]
__global__ __launch_bounds__(256) void gemm_nt(const bf16* __restrict__ A, const bf16* __restrict__ Bf,
                                               bf16* __restrict__ C, int Kdim, int Kt) {
  const int lane = threadIdx.x & 63, wave = threadIdx.x >> 6;
  const int lr = lane & 15, lh = lane >> 4;
  const int mb = blockIdx.x * 64;
  const int ntb = blockIdx.y * 16 + wave * 4;
  f32x4 acc[4][4] = {};
  for (int kt = 0; kt < Kt; ++kt) {
    bf16x8 a[4], b[4];
#pragma unroll
    for (int mt = 0; mt < 4; ++mt)
      a[mt] = *(const bf16x8*)(A + (size_t)(mb + mt * 16 + lr) * Kdim + kt * 32 + lh * 8);
#pragma unroll
    for (int q = 0; q < 4; ++q)
      b[q] = *(const bf16x8*)(Bf + ((size_t)(ntb + q) * Kt + kt) * 512 + lane * 8);
#pragma unroll
    for (int mt = 0; mt < 4; ++mt)
#pragma unroll
      for (int q = 0; q < 4; ++q)
        acc[mt][q] = __builtin_amdgcn_mfma_f32_16x16x32_bf16(a[mt], b[q], acc[mt][q], 0, 0, 0);
  }
  const int t = blockIdx.x;  // rows [mb, mb+64) are exactly timestep t
#pragma unroll
  for (int q = 0; q < 4; ++q) {
    const int colbase = (ntb + q) * 16;
    const int dirq = colbase >> 11, gq = (colbase >> 9) & 3, jbq = (colbase >> 4) & 31;
    unsigned short vals[16];
#pragma unroll
    for (int mt = 0; mt < 4; ++mt)
#pragma unroll
      for (int r = 0; r < 4; ++r) {
        bf16 hb = __float2bfloat16(acc[mt][q][r]);
        vals[mt * 4 + r] = *(unsigned short*)&hb;
      }
    bf16* outp = C + ((((size_t)t * 2 + dirq) * 32 + jbq) * 4 + gq) * 1024 + lane * 16;
    *(bf16x8*)(outp) = *(const bf16x8*)(vals);
    *(bf16x8*)(outp + 8) = *(const bf16x8*)(vals + 8);
  }
}

// ---------------- cooperative bidirectional LSTM layer (reg h-frags, no LDS A-tile) ----------------
// grid(32 jb-tiles, 2 dirs), 256 threads (wave = gate). Slot-flag barrier (packed, all-wave
// poll via L2-bypassing atomic loads). Whh frags in registers (16 x bf16x8, proven no-remat).
// h_{t-1} fragments loaded per kt straight to registers with PLAIN CACHED loads: correct
// because each dispatch begins cache-invalidated and every h line is first-touched only
// after its producer's sc0sc1 write-through (flag-ordered). preP packed: one 32B load/thread.
__global__ __launch_bounds__(256, 1) void lstm_reg(const bf16* __restrict__ preP, const bf16* __restrict__ whh,
                                                   const float* __restrict__ bias, bf16* __restrict__ hout,
                                                   unsigned int* __restrict__ flags) {
  const int tid = threadIdx.x, lane = tid & 63, wave = tid >> 6;
  const int lr = lane & 15, lh = lane >> 4;
  const int jb = blockIdx.x, dir = blockIdx.y;
  unsigned int* flg = flags + dir * 64;
  unsigned int* myflg = flg + jb;
  __shared__ float xch[4 * 64 * 17];  // [gate][row][16 cols], stride-17 pad
  __shared__ float cst[64 * 16];      // c-state fp32, persistent across steps
  for (int i = tid; i < 1024; i += 256) cst[i] = 0.f;
  const float bb = bias[dir * 2048 + wave * 512 + jb * 16 + lr];
  const bf16* wbase = whh + ((size_t)(dir * 128 + wave * 32 + jb) * 16) * 512 + lane * 8;

  // recurrent weights resident in registers (16 frags = 64 VGPRs)
  bf16x8 wfrag[16];
#pragma unroll
  for (int kt = 0; kt < 16; ++kt) wfrag[kt] = *(const bf16x8*)(wbase + kt * 512);

  // pre-activation for first step (packed: one 32B load)
  bf16x16 pp = *(const bf16x16*)(preP + ((((size_t)(dir ? 255 : 0) * 2 + dir) * 32 + jb) * 4 + wave) * 1024 +
                                 lane * 16);

  const int srow = tid >> 2, sq = tid & 3;  // cell mapping: row srow, cols sq*4..+3

  for (int s = 0; s < 256; ++s) {
    const int t = dir ? 255 - s : s;
    f32x4 acc[4] = {};
    if (s > 0) {
      // wait: all 32 producer blocks of this direction finished step s-1
      const unsigned int tgt = (unsigned int)s;
      for (;;) {
        unsigned int v = __hip_atomic_load(flg + (lane & 31), __ATOMIC_RELAXED, __HIP_MEMORY_SCOPE_AGENT);
        if (__all((int)(v >= tgt))) break;
      }
      asm volatile("" ::: "memory");  // keep h loads after the poll
      const int tp = dir ? t + 1 : t - 1;
      const bf16* hp = hout + (size_t)tp * 65536 + dir * 512 + (size_t)lr * 1024 + lh * 8;
#pragma unroll 4
      for (int kt = 0; kt < 16; ++kt) {
        bf16x8 a0 = *(const bf16x8*)(hp + kt * 32);
        bf16x8 a1 = *(const bf16x8*)(hp + 16384 + kt * 32);
        bf16x8 a2 = *(const bf16x8*)(hp + 32768 + kt * 32);
        bf16x8 a3 = *(const bf16x8*)(hp + 49152 + kt * 32);
        acc[0] = __builtin_amdgcn_mfma_f32_16x16x32_bf16(a0, wfrag[kt], acc[0], 0, 0, 0);
        acc[1] = __builtin_amdgcn_mfma_f32_16x16x32_bf16(a1, wfrag[kt], acc[1], 0, 0, 0);
        acc[2] = __builtin_amdgcn_mfma_f32_16x16x32_bf16(a2, wfrag[kt], acc[2], 0, 0, 0);
        acc[3] = __builtin_amdgcn_mfma_f32_16x16x32_bf16(a3, wfrag[kt], acc[3], 0, 0, 0);
      }
    }
#pragma unroll
    for (int mt = 0; mt < 4; ++mt)
#pragma unroll
      for (int r = 0; r < 4; ++r) {
        bf16 pv; *(unsigned short*)&pv = (unsigned short)pp[mt * 4 + r];
        xch[(wave * 64 + mt * 16 + lh * 4 + r) * 17 + lr] = acc[mt][r] + bb + __bfloat162float(pv);
      }
    __syncthreads();
    {
      ull pk = 0;
#pragma unroll
      for (int i = 0; i < 4; ++i) {
        int col = sq * 4 + i;
        float gi = xch[(0 * 64 + srow) * 17 + col];
        float gf = xch[(1 * 64 + srow) * 17 + col];
        float gg = xch[(2 * 64 + srow) * 17 + col];
        float go = xch[(3 * 64 + srow) * 17 + col];
        float c = cst[srow * 16 + col];
        float cn = sigm(gf) * c + sigm(gi) * tanh_(gg);
        cst[srow * 16 + col] = cn;
        float h = sigm(go) * tanh_(cn);
        bf16 hb = __float2bfloat16(h);
        pk |= (ull)(*(unsigned short*)&hb) << (16 * i);
      }
      ull* hq = (ull*)(hout + ((size_t)t * 64 + srow) * 1024 + dir * 512 + jb * 16 + sq * 4);
      __hip_atomic_store(hq, pk, __ATOMIC_RELAXED, __HIP_MEMORY_SCOPE_AGENT);
    }
    // release: drain own write-through stores, join waves, publish epoch (no RMW)
    asm volatile("s_waitcnt vmcnt(0)" ::: "memory");
    __syncthreads();
    if (tid == 0)
      __hip_atomic_store(myflg, (unsigned int)(s + 1), __ATOMIC_RELAXED, __HIP_MEMORY_SCOPE_AGENT);
    // prefetch next step's packed pre (hides under the next poll)
    if (s < 255) {
      const int tn = dir ? t - 1 : t + 1;
      pp = *(const bf16x16*)(preP + ((((size_t)tn * 2 + dir) * 32 + jb) * 4 + wave) * 1024 + lane * 16);
    }
  }
}

// ---------------- emit projection: emit[16384][64] = h1 @ WoutB + bout, masked ----------------
__global__ __launch_bounds__(256) void emit_k(const bf16* __restrict__ h1, const bf16* __restrict__ wo,
                                              const float* __restrict__ bout, const int* __restrict__ x,
                                              float* __restrict__ emit) {
  const int tid = threadIdx.x, lane = tid & 63, wave = tid >> 6;
  const int lr = lane & 15, lh = lane >> 4;
  const int mb = blockIdx.x * 64 + wave * 16;
  f32x4 acc[4] = {};
  for (int kt = 0; kt < 32; ++kt) {
    bf16x8 a = *(const bf16x8*)(h1 + (size_t)(mb + lr) * 1024 + kt * 32 + lh * 8);
#pragma unroll
    for (int q = 0; q < 4; ++q) {
      bf16x8 b = *(const bf16x8*)(wo + ((size_t)(q * 32 + kt) * 64 + lane) * 8);
      acc[q] = __builtin_amdgcn_mfma_f32_16x16x32_bf16(a, b, acc[q], 0, 0, 0);
    }
  }
#pragma unroll
  for (int q = 0; q < 4; ++q)
#pragma unroll
    for (int r = 0; r < 4; ++r) {
      int row = mb + lh * 4 + r;
      int col = q * 16 + lr;
      int tt = row >> 6, bi = row & 63;
      float m = (x[bi * 256 + tt] > 0) ? 1.f : 0.f;
      emit[(size_t)row * 64 + col] = (acc[q][r] + bout[col]) * m;
    }
}

// ---------------- CRF forward + gold score, one block per batch element ----------------
__global__ __launch_bounds__(256) void crf_k(const float* __restrict__ emit, const float* __restrict__ trans,
                                             const int* __restrict__ x, const int* __restrict__ y0,
                                             float* __restrict__ out) {
  const int b = blockIdx.x, tid = threadIdx.x;
  __shared__ float tr[4096];
  __shared__ float sc[2][64];
  __shared__ float pm[4][64], ps[4][64];
  __shared__ float redw[4];
  for (int i = tid; i < 4096; i += 256) tr[i] = trans[i];
  if (tid < 64) sc[0][tid] = (tid == 2) ? 0.f : NEGV;  // SOS=2
  __syncthreads();
  {
    const int t = tid;
    const int tag = y0[b * 256 + t];
    const int prev = t ? y0[b * 256 + t - 1] : 2;
    const float m = (x[b * 256 + t] > 0) ? 1.f : 0.f;
    float g = emit[((size_t)t * 64 + b) * 64 + tag] + tr[tag * 64 + prev] * m;
    for (int o = 32; o; o >>= 1) g += __shfl_down(g, o, 64);
    if ((tid & 63) == 0) redw[tid >> 6] = g;
  }
  __syncthreads();
  const float gold = redw[0] + redw[1] + redw[2] + redw[3];
  const int j = tid & 63, kq = tid >> 6;
  int cur = 0;
  for (int t = 0; t < 256; ++t) {
    const float* trj = tr + j * 64 + kq * 16;
    const float* scc = sc[cur] + kq * 16;
    float v[16];
    float mx = -3.0e38f;
#pragma unroll
    for (int k = 0; k < 16; ++k) {
      v[k] = scc[k] + trj[k];
      mx = fmaxf(mx, v[k]);
    }
    float sm = 0.f;
#pragma unroll
    for (int k = 0; k < 16; ++k) sm += __expf(v[k] - mx);
    pm[kq][j] = mx;
    ps[kq][j] = sm;
    __syncthreads();
    if (kq == 0) {
      float M = fmaxf(fmaxf(pm[0][j], pm[1][j]), fmaxf(pm[2][j], pm[3][j]));
      float S = ps[0][j] * __expf(pm[0][j] - M) + ps[1][j] * __expf(pm[1][j] - M) +
                ps[2][j] * __expf(pm[2][j] - M) + ps[3][j] * __expf(pm[3][j] - M);
      float nv = M + __logf(S) + emit[((size_t)t * 64 + b) * 64 + j];
      sc[cur ^ 1][j] = (x[b * 256 + t] > 0) ? nv : sc[cur][j];
    }
    __syncthreads();
    cur ^= 1;
  }
  if (tid < 64) {
    float v2 = sc[cur][tid];
    float M = v2;
    for (int o = 32; o; o >>= 1) M = fmaxf(M, __shfl_xor(M, o, 64));
    float s2 = __expf(v2 - M);
    for (int o = 32; o; o >>= 1) s2 += __shfl_xor(s2, o, 64);
    if (tid == 0) out[b] = M + __logf(s2) - gold;
  }
}

// ---------------- launch ----------------
extern "C" void kernel_launch(void* const* d_in, const int* in_sizes, int n_in, void* d_out, int out_size,
                              void* d_ws, size_t ws_size, hipStream_t stream) {
  (void)in_sizes; (void)n_in; (void)out_size; (void)ws_size;
  const int* x = (const int*)d_in[0];
  const int* y0 = (const int*)d_in[1];
  const float* embed = (const float*)d_in[2];
  const float* Wih0f = (const float*)d_in[3];
  const float* Whh0f = (const float*)d_in[4];
  const float* b0f = (const float*)d_in[5];
  const float* Wih0b = (const float*)d_in[6];
  const float* Whh0b = (const float*)d_in[7];
  const float* b0b = (const float*)d_in[8];
  const float* Wih1f = (const float*)d_in[9];
  const float* Whh1f = (const float*)d_in[10];
  const float* b1f = (const float*)d_in[11];
  const float* Wih1b = (const float*)d_in[12];
  const float* Whh1b = (const float*)d_in[13];
  const float* b1b = (const float*)d_in[14];
  const float* Wout = (const float*)d_in[15];
  const float* bout = (const float*)d_in[16];
  const float* trans = (const float*)d_in[17];

  char* p = (char*)d_ws;
  auto take = [&](size_t n) { char* r = p; p += (n + 255) & ~(size_t)255; return r; };
  unsigned int* flags = (unsigned int*)take(2048 * sizeof(unsigned int));  // [layer][dir][32 slots]
  bf16* xs = (bf16*)take(16384ull * 320 * 2);
  bf16* preP = (bf16*)take(16384ull * 4096 * 2);
  bf16* h0 = (bf16*)take(16384ull * 1024 * 2);
  bf16* h1 = (bf16*)take(16384ull * 1024 * 2);
  float* emitb = (float*)take(16384ull * 64 * 4);
  bf16* W0B = (bf16*)take(4096ull * 320 * 2);
  bf16* W1B = (bf16*)take(4096ull * 1024 * 2);
  bf16* WhhB = (bf16*)take(4ull * 1048576 * 2);
  bf16* WoB = (bf16*)take(64ull * 1024 * 2);
  float* bias0 = (float*)take(4096 * 4);
  float* bias1 = (float*)take(4096 * 4);

  hipMemsetAsync(flags, 0, 2048 * sizeof(unsigned int), stream);
  hipLaunchKernelGGL(pack_w0, dim3(5120), dim3(256), 0, stream, Wih0f, Wih0b, W0B);
  hipLaunchKernelGGL(pack_whh, dim3(4096), dim3(256), 0, stream, Whh0f, WhhB + 0ull * 1048576);
  hipLaunchKernelGGL(pack_whh, dim3(4096), dim3(256), 0, stream, Whh0b, WhhB + 1ull * 1048576);
  hipLaunchKernelGGL(pack_whh, dim3(4096), dim3(256), 0, stream, Whh1f, WhhB + 2ull * 1048576);
  hipLaunchKernelGGL(pack_whh, dim3(4096), dim3(256), 0, stream, Whh1b, WhhB + 3ull * 1048576);
  hipLaunchKernelGGL(pack_w1, dim3(16384), dim3(256), 0, stream, Wih1f, Wih1b, W1B);
  hipLaunchKernelGGL(pack_wout, dim3(256), dim3(256), 0, stream, Wout, WoB);
  hipLaunchKernelGGL(pack_bias, dim3(16), dim3(256), 0, stream, b0f, b0b, bias0);
  hipLaunchKernelGGL(pack_bias, dim3(16), dim3(256), 0, stream, b1f, b1b, bias1);
  hipLaunchKernelGGL(embed_k, dim3(20480), dim3(256), 0, stream, x, embed, xs);

  hipLaunchKernelGGL(gemm_nt, dim3(256, 16), dim3(256), 0, stream, xs, W0B, preP, 320, 10);
  {
    const bf16* a0 = preP; const bf16* a1 = WhhB; const float* a2 = bias0; bf16* a3 = h0;
    unsigned int* a4 = flags;  // layer0 slots
    void* args[] = {&a0, &a1, &a2, &a3, &a4};
    hipLaunchCooperativeKernel((void*)lstm_reg, dim3(32, 2), dim3(256), args, 0, stream);
  }
  hipLaunchKernelGGL(gemm_nt, dim3(256, 16), dim3(256), 0, stream, h0, W1B, preP, 1024, 32);
  {
    const bf16* a0 = preP; const bf16* a1 = WhhB + 2ull * 1048576; const float* a2 = bias1; bf16* a3 = h1;
    unsigned int* a4 = flags + 1024;  // layer1 slots
    void* args[] = {&a0, &a1, &a2, &a3, &a4};
    hipLaunchCooperativeKernel((void*)lstm_reg, dim3(32, 2), dim3(256), args, 0, stream);
  }
  hipLaunchKernelGGL(emit_k, dim3(256), dim3(256), 0, stream, h1, WoB, bout, x, emitb);
  hipLaunchKernelGGL(crf_k, dim3(64), dim3(256), 0, stream, emitb, trans, x, y0, (float*)d_out);
}

// Round 9
// 3500.697 us; speedup vs baseline: 3.0504x; 2.6522x over previous
//
#include <hip/hip_runtime.h>
#include <hip/hip_bf16.h>

typedef short bf16x8 __attribute__((ext_vector_type(8)));
typedef short bf16x16 __attribute__((ext_vector_type(16)));
typedef float f32x4 __attribute__((ext_vector_type(4)));
typedef __hip_bfloat16 bf16;
typedef unsigned long long ull;

#define NEGV -10000.0f

// Problem dims: B=64, T=256, E=300, H=500, K=64(tags), V=32000
// Padded: Ep=320, Hp=512, layer-1 input 2*Hp=1024, gate width 4096 = 2dir*4gate*512

__device__ __forceinline__ float sigm(float v) { return 1.0f / (1.0f + __expf(-v)); }
__device__ __forceinline__ float tanh_(float v) { float e = __expf(2.0f * v); return 1.0f - 2.0f / (e + 1.0f); }

// async global->LDS, 16B per lane, wave-uniform LDS base + lane*16
__device__ __forceinline__ void async_load16(const bf16* g, const char* l) {
  __builtin_amdgcn_global_load_lds((const __attribute__((address_space(1))) void*)g,
                                   (__attribute__((address_space(3))) void*)l, 16, 0, 0);
}

// ---------------- weight packing into MFMA fragment-linear layout ----------------
// B-frag layout: dst[((nt*Kt + kt)*64 + lane)*8 + u] = B[kt*32 + (lane>>4)*8 + u][nt*16 + (lane&15)]

__global__ __launch_bounds__(256) void pack_w0(const float* __restrict__ wf, const float* __restrict__ wb,
                                               bf16* __restrict__ dst) {
  int idx = blockIdx.x * 256 + threadIdx.x;            // 4096*320 = 1310720
  int u = idx & 7, lane = (idx >> 3) & 63, rem = idx >> 9;
  int kt = rem % 10, nt = rem / 10;
  int n = (nt << 4) + (lane & 15), k = (kt << 5) + ((lane >> 4) << 3) + u;
  int d = n >> 11, g = (n >> 9) & 3, j = n & 511;
  float v = 0.f;
  if (j < 500 && k < 300) v = (d ? wb : wf)[(g * 500 + j) * 300 + k];
  dst[idx] = __float2bfloat16(v);
}

__global__ __launch_bounds__(256) void pack_whh(const float* __restrict__ w, bf16* __restrict__ dst) {
  int idx = blockIdx.x * 256 + threadIdx.x;            // 2048*512 = 1048576
  int u = idx & 7, lane = (idx >> 3) & 63, rem = idx >> 9;
  int kt = rem & 15, nt = rem >> 4;
  int n = (nt << 4) + (lane & 15), k = (kt << 5) + ((lane >> 4) << 3) + u;
  int g = n >> 9, j = n & 511;
  float v = 0.f;
  if (j < 500 && k < 500) v = w[(g * 500 + j) * 500 + k];
  dst[idx] = __float2bfloat16(v);
}

__global__ __launch_bounds__(256) void pack_w1(const float* __restrict__ wf, const float* __restrict__ wb,
                                               bf16* __restrict__ dst) {
  int idx = blockIdx.x * 256 + threadIdx.x;            // 4096*1024 = 4194304
  int u = idx & 7, lane = (idx >> 3) & 63, rem = idx >> 9;
  int kt = rem & 31, nt = rem >> 5;
  int n = (nt << 4) + (lane & 15), k = (kt << 5) + ((lane >> 4) << 3) + u;
  int d = n >> 11, g = (n >> 9) & 3, j = n & 511;
  int kk = k & 511;
  int ks = (k < 512) ? kk : 500 + kk;
  float v = 0.f;
  if (j < 500 && kk < 500) v = (d ? wb : wf)[(g * 500 + j) * 1000 + ks];
  dst[idx] = __float2bfloat16(v);
}

__global__ __launch_bounds__(256) void pack_wout(const float* __restrict__ w, bf16* __restrict__ dst) {
  int idx = blockIdx.x * 256 + threadIdx.x;            // 4*32*512 = 65536
  int u = idx & 7, lane = (idx >> 3) & 63, rem = idx >> 9;
  int kt = rem & 31, nt = rem >> 5;
  int n = (nt << 4) + (lane & 15), k = (kt << 5) + ((lane >> 4) << 3) + u;
  int kk = k & 511;
  int ks = (k < 512) ? kk : 500 + kk;
  float v = 0.f;
  if (kk < 500) v = w[n * 1000 + ks];
  dst[idx] = __float2bfloat16(v);
}

__global__ __launch_bounds__(256) void pack_bias(const float* __restrict__ bf_, const float* __restrict__ bb_,
                                                 float* __restrict__ dst) {
  int idx = blockIdx.x * 256 + threadIdx.x;            // 4096
  int d = idx >> 11, g = (idx >> 9) & 3, j = idx & 511;
  dst[idx] = (j < 500) ? (d ? bb_ : bf_)[g * 500 + j] : 0.f;
}

// ---------------- embedding gather -> bf16 [T*B][320] ----------------
__global__ __launch_bounds__(256) void embed_k(const int* __restrict__ x, const float* __restrict__ em,
                                               bf16* __restrict__ xs) {
  int idx = blockIdx.x * 256 + threadIdx.x;            // 16384*320
  int e = idx % 320;
  int row = idx / 320;
  int t = row >> 6, b = row & 63;
  float v = 0.f;
  if (e < 300) {
    int xv = x[b * 256 + t];
    v = em[(size_t)xv * 300 + e];
  }
  xs[idx] = __float2bfloat16(v);
}

// ---------------- MFMA GEMM: preP = A[16384][Kdim] @ Bfrag, epilogue scatters into
// per-thread-contiguous lstm consumption layout:
// preP[(((t*2+dir)*32+jb)*4+gate)*1024 + lane*16 + (mt*4+r)]
__global__ __launch_bounds__(256) void gemm_nt(const bf16* __restrict__ A, const bf16* __restrict__ Bf,
                                               bf16* __restrict__ C, int Kdim, int Kt) {
  const int lane = threadIdx.x & 63, wave = threadIdx.x >> 6;
  const int lr = lane & 15, lh = lane >> 4;
  const int mb = blockIdx.x * 64;
  const int ntb = blockIdx.y * 16 + wave * 4;
  f32x4 acc[4][4] = {};
  for (int kt = 0; kt < Kt; ++kt) {
    bf16x8 a[4], b[4];
#pragma unroll
    for (int mt = 0; mt < 4; ++mt)
      a[mt] = *(const bf16x8*)(A + (size_t)(mb + mt * 16 + lr) * Kdim + kt * 32 + lh * 8);
#pragma unroll
    for (int q = 0; q < 4; ++q)
      b[q] = *(const bf16x8*)(Bf + ((size_t)(ntb + q) * Kt + kt) * 512 + lane * 8);
#pragma unroll
    for (int mt = 0; mt < 4; ++mt)
#pragma unroll
      for (int q = 0; q < 4; ++q)
        acc[mt][q] = __builtin_amdgcn_mfma_f32_16x16x32_bf16(a[mt], b[q], acc[mt][q], 0, 0, 0);
  }
  const int t = blockIdx.x;  // rows [mb, mb+64) are exactly timestep t
#pragma unroll
  for (int q = 0; q < 4; ++q) {
    const int colbase = (ntb + q) * 16;
    const int dirq = colbase >> 11, gq = (colbase >> 9) & 3, jbq = (colbase >> 4) & 31;
    unsigned short vals[16];
#pragma unroll
    for (int mt = 0; mt < 4; ++mt)
#pragma unroll
      for (int r = 0; r < 4; ++r) {
        bf16 hb = __float2bfloat16(acc[mt][q][r]);
        vals[mt * 4 + r] = *(unsigned short*)&hb;
      }
    bf16* outp = C + ((((size_t)t * 2 + dirq) * 32 + jbq) * 4 + gq) * 1024 + lane * 16;
    *(bf16x8*)(outp) = *(const bf16x8*)(vals);
    *(bf16x8*)(outp + 8) = *(const bf16x8*)(vals + 8);
  }
}

// ---------------- cooperative bidirectional LSTM layer (R5 structure, optional batch-split) ----
// SPLIT=0: R5-exact. grid(32 jb, 2 dir): 64KB h tile staged per block via global_load_lds,
//   swizzled LDS reads feed MFMA, wfrag in regs (LDS-A path keeps them resident - proven).
// SPLIT=1: grid(32 jb, 2 dir, 2 half): block owns 32 batch rows. Staging/MFMA/cell all
//   halve; flag groups stay 32 producers (group = dir x half, batch rows never mix).
template <int SPLIT>
__global__ __launch_bounds__(256, 1) void lstm_st(const bf16* __restrict__ preP, const bf16* __restrict__ whh,
                                                  const float* __restrict__ bias, bf16* __restrict__ hout,
                                                  unsigned int* __restrict__ flags) {
  constexpr int ROWS = SPLIT ? 32 : 64;   // batch rows per block
  constexpr int MT = SPLIT ? 2 : 4;       // 16-row MFMA tiles per block
  const int tid = threadIdx.x, lane = tid & 63, wave = tid >> 6;
  const int lr = lane & 15, lh = lane >> 4;
  const int jb = blockIdx.x, dir = blockIdx.y, half = SPLIT ? blockIdx.z : 0;
  unsigned int* flg = flags + (dir * 2 + half) * 64;
  unsigned int* myflg = flg + jb;
  __shared__ __align__(16) char hlds[ROWS * 1024];  // h tile, swizzle-stored
  __shared__ float xch[4 * ROWS * 17];              // [gate][local row][16 cols] pad 17
  __shared__ float cst[ROWS * 16];                  // c-state fp32, persistent
  for (int i = tid; i < ROWS * 16; i += 256) cst[i] = 0.f;
  const float bb = bias[dir * 2048 + wave * 512 + jb * 16 + lr];
  const bf16* wbase = whh + ((size_t)(dir * 128 + wave * 32 + jb) * 16) * 512 + lane * 8;

  // recurrent weights resident in registers (16 frags = 64 VGPRs; LDS-A path => no remat)
  bf16x8 wfrag[16];
#pragma unroll
  for (int kt = 0; kt < 16; ++kt) wfrag[kt] = *(const bf16x8*)(wbase + kt * 512);

  // packed pre-activations for first step: one vector load
  unsigned short pf[16];
  {
    const int t0 = dir ? 255 : 0;
    const bf16* pb = preP + ((((size_t)t0 * 2 + dir) * 32 + jb) * 4 + wave) * 1024 + lane * 16;
    if (SPLIT) *(bf16x8*)pf = *(const bf16x8*)(pb + half * 8);
    else       *(bf16x16*)pf = *(const bf16x16*)pb;
  }

  for (int s = 0; s < 256; ++s) {
    const int t = dir ? 255 - s : s;
    f32x4 acc[MT] = {};
    if (s > 0) {
      // wait: all 32 producer blocks of this (dir,half) group finished step s-1
      const unsigned int tgt = (unsigned int)s;
      for (;;) {
        unsigned int v = __hip_atomic_load(flg + (lane & 31), __ATOMIC_RELAXED, __HIP_MEMORY_SCOPE_AGENT);
        if (__all((int)(v >= tgt))) break;
      }
      asm volatile("" ::: "memory");
      const int tp = dir ? t + 1 : t - 1;
      const bf16* hp = hout + (size_t)tp * 65536 + dir * 512;
      // async stage: wave w covers local rows i*4+w; swizzled global source -> linear LDS
#pragma unroll
      for (int i = 0; i < ROWS / 4; ++i) {
        const int row = i * 4 + wave;                     // local row
        const int m = (row & 7) << 4;
        const bf16* g = hp + (size_t)(half * 32 + row) * 1024 + (((lane * 16) ^ m) >> 1);
        async_load16(g, hlds + row * 1024);
      }
      asm volatile("s_waitcnt vmcnt(0)" ::: "memory");
      __syncthreads();
#pragma unroll 4
      for (int kt = 0; kt < 16; ++kt) {
#pragma unroll
        for (int mt = 0; mt < MT; ++mt) {
          const int row = mt * 16 + lr;
          const int cb = (kt * 64 + lh * 16) ^ ((row & 7) << 4);
          const bf16x8 afr = *(const bf16x8*)(hlds + row * 1024 + cb);
          acc[mt] = __builtin_amdgcn_mfma_f32_16x16x32_bf16(afr, wfrag[kt], acc[mt], 0, 0, 0);
        }
      }
    }
#pragma unroll
    for (int mt = 0; mt < MT; ++mt)
#pragma unroll
      for (int r = 0; r < 4; ++r) {
        bf16 pv; *(unsigned short*)&pv = pf[mt * 4 + r];
        xch[(wave * ROWS + mt * 16 + lh * 4 + r) * 17 + lr] = acc[mt][r] + bb + __bfloat162float(pv);
      }
    __syncthreads();
    if (SPLIT) {
      // 512 cells / 256 threads: row=tid>>3 (local), cols 2*(tid&7), +1 -> one 4B store
      const int row = tid >> 3, c0 = (tid & 7) * 2;
      unsigned int pk = 0;
#pragma unroll
      for (int i = 0; i < 2; ++i) {
        int col = c0 + i;
        float gi = xch[(0 * ROWS + row) * 17 + col];
        float gf = xch[(1 * ROWS + row) * 17 + col];
        float gg = xch[(2 * ROWS + row) * 17 + col];
        float go = xch[(3 * ROWS + row) * 17 + col];
        float c = cst[row * 16 + col];
        float cn = sigm(gf) * c + sigm(gi) * tanh_(gg);
        cst[row * 16 + col] = cn;
        bf16 hb = __float2bfloat16(sigm(go) * tanh_(cn));
        pk |= (unsigned int)(*(unsigned short*)&hb) << (16 * i);
      }
      unsigned int* hq =
          (unsigned int*)(hout + ((size_t)t * 64 + half * 32 + row) * 1024 + dir * 512 + jb * 16 + c0);
      __hip_atomic_store(hq, pk, __ATOMIC_RELAXED, __HIP_MEMORY_SCOPE_AGENT);
    } else {
      // 1024 cells / 256 threads: row=tid>>2, cols 4*(tid&3).. -> one 8B store (R5-exact)
      const int row = tid >> 2, c0 = (tid & 3) * 4;
      ull pk = 0;
#pragma unroll
      for (int i = 0; i < 4; ++i) {
        int col = c0 + i;
        float gi = xch[(0 * ROWS + row) * 17 + col];
        float gf = xch[(1 * ROWS + row) * 17 + col];
        float gg = xch[(2 * ROWS + row) * 17 + col];
        float go = xch[(3 * ROWS + row) * 17 + col];
        float c = cst[row * 16 + col];
        float cn = sigm(gf) * c + sigm(gi) * tanh_(gg);
        cst[row * 16 + col] = cn;
        bf16 hb = __float2bfloat16(sigm(go) * tanh_(cn));
        pk |= (ull)(*(unsigned short*)&hb) << (16 * i);
      }
      ull* hq = (ull*)(hout + ((size_t)t * 64 + row) * 1024 + dir * 512 + jb * 16 + c0);
      __hip_atomic_store(hq, pk, __ATOMIC_RELAXED, __HIP_MEMORY_SCOPE_AGENT);
    }
    // release: drain write-through stores, join waves, publish epoch
    asm volatile("s_waitcnt vmcnt(0)" ::: "memory");
    __syncthreads();
    if (tid == 0)
      __hip_atomic_store(myflg, (unsigned int)(s + 1), __ATOMIC_RELAXED, __HIP_MEMORY_SCOPE_AGENT);
    // prefetch next step's packed pre (hides under the next poll)
    if (s < 255) {
      const int tn = dir ? t - 1 : t + 1;
      const bf16* pb = preP + ((((size_t)tn * 2 + dir) * 32 + jb) * 4 + wave) * 1024 + lane * 16;
      if (SPLIT) *(bf16x8*)pf = *(const bf16x8*)(pb + half * 8);
      else       *(bf16x16*)pf = *(const bf16x16*)pb;
    }
  }
}

// ---------------- emit projection: emit[16384][64] = h1 @ WoutB + bout, masked ----------------
__global__ __launch_bounds__(256) void emit_k(const bf16* __restrict__ h1, const bf16* __restrict__ wo,
                                              const float* __restrict__ bout, const int* __restrict__ x,
                                              float* __restrict__ emit) {
  const int tid = threadIdx.x, lane = tid & 63, wave = tid >> 6;
  const int lr = lane & 15, lh = lane >> 4;
  const int mb = blockIdx.x * 64 + wave * 16;
  f32x4 acc[4] = {};
  for (int kt = 0; kt < 32; ++kt) {
    bf16x8 a = *(const bf16x8*)(h1 + (size_t)(mb + lr) * 1024 + kt * 32 + lh * 8);
#pragma unroll
    for (int q = 0; q < 4; ++q) {
      bf16x8 b = *(const bf16x8*)(wo + ((size_t)(q * 32 + kt) * 64 + lane) * 8);
      acc[q] = __builtin_amdgcn_mfma_f32_16x16x32_bf16(a, b, acc[q], 0, 0, 0);
    }
  }
#pragma unroll
  for (int q = 0; q < 4; ++q)
#pragma unroll
    for (int r = 0; r < 4; ++r) {
      int row = mb + lh * 4 + r;
      int col = q * 16 + lr;
      int tt = row >> 6, bi = row & 63;
      float m = (x[bi * 256 + tt] > 0) ? 1.f : 0.f;
      emit[(size_t)row * 64 + col] = (acc[q][r] + bout[col]) * m;
    }
}

// ---------------- CRF forward + gold score, one block per batch element ----------------
__global__ __launch_bounds__(256) void crf_k(const float* __restrict__ emit, const float* __restrict__ trans,
                                             const int* __restrict__ x, const int* __restrict__ y0,
                                             float* __restrict__ out) {
  const int b = blockIdx.x, tid = threadIdx.x;
  __shared__ float tr[4096];
  __shared__ float sc[2][64];
  __shared__ float pm[4][64], ps[4][64];
  __shared__ float redw[4];
  for (int i = tid; i < 4096; i += 256) tr[i] = trans[i];
  if (tid < 64) sc[0][tid] = (tid == 2) ? 0.f : NEGV;  // SOS=2
  __syncthreads();
  {
    const int t = tid;
    const int tag = y0[b * 256 + t];
    const int prev = t ? y0[b * 256 + t - 1] : 2;
    const float m = (x[b * 256 + t] > 0) ? 1.f : 0.f;
    float g = emit[((size_t)t * 64 + b) * 64 + tag] + tr[tag * 64 + prev] * m;
    for (int o = 32; o; o >>= 1) g += __shfl_down(g, o, 64);
    if ((tid & 63) == 0) redw[tid >> 6] = g;
  }
  __syncthreads();
  const float gold = redw[0] + redw[1] + redw[2] + redw[3];
  const int j = tid & 63, kq = tid >> 6;
  int cur = 0;
  for (int t = 0; t < 256; ++t) {
    const float* trj = tr + j * 64 + kq * 16;
    const float* scc = sc[cur] + kq * 16;
    float v[16];
    float mx = -3.0e38f;
#pragma unroll
    for (int k = 0; k < 16; ++k) {
      v[k] = scc[k] + trj[k];
      mx = fmaxf(mx, v[k]);
    }
    float sm = 0.f;
#pragma unroll
    for (int k = 0; k < 16; ++k) sm += __expf(v[k] - mx);
    pm[kq][j] = mx;
    ps[kq][j] = sm;
    __syncthreads();
    if (kq == 0) {
      float M = fmaxf(fmaxf(pm[0][j], pm[1][j]), fmaxf(pm[2][j], pm[3][j]));
      float S = ps[0][j] * __expf(pm[0][j] - M) + ps[1][j] * __expf(pm[1][j] - M) +
                ps[2][j] * __expf(pm[2][j] - M) + ps[3][j] * __expf(pm[3][j] - M);
      float nv = M + __logf(S) + emit[((size_t)t * 64 + b) * 64 + j];
      sc[cur ^ 1][j] = (x[b * 256 + t] > 0) ? nv : sc[cur][j];
    }
    __syncthreads();
    cur ^= 1;
  }
  if (tid < 64) {
    float v2 = sc[cur][tid];
    float M = v2;
    for (int o = 32; o; o >>= 1) M = fmaxf(M, __shfl_xor(M, o, 64));
    float s2 = __expf(v2 - M);
    for (int o = 32; o; o >>= 1) s2 += __shfl_xor(s2, o, 64);
    if (tid == 0) out[b] = M + __logf(s2) - gold;
  }
}

// ---------------- launch ----------------
extern "C" void kernel_launch(void* const* d_in, const int* in_sizes, int n_in, void* d_out, int out_size,
                              void* d_ws, size_t ws_size, hipStream_t stream) {
  (void)in_sizes; (void)n_in; (void)out_size; (void)ws_size;
  const int* x = (const int*)d_in[0];
  const int* y0 = (const int*)d_in[1];
  const float* embed = (const float*)d_in[2];
  const float* Wih0f = (const float*)d_in[3];
  const float* Whh0f = (const float*)d_in[4];
  const float* b0f = (const float*)d_in[5];
  const float* Wih0b = (const float*)d_in[6];
  const float* Whh0b = (const float*)d_in[7];
  const float* b0b = (const float*)d_in[8];
  const float* Wih1f = (const float*)d_in[9];
  const float* Whh1f = (const float*)d_in[10];
  const float* b1f = (const float*)d_in[11];
  const float* Wih1b = (const float*)d_in[12];
  const float* Whh1b = (const float*)d_in[13];
  const float* b1b = (const float*)d_in[14];
  const float* Wout = (const float*)d_in[15];
  const float* bout = (const float*)d_in[16];
  const float* trans = (const float*)d_in[17];

  char* p = (char*)d_ws;
  auto take = [&](size_t n) { char* r = p; p += (n + 255) & ~(size_t)255; return r; };
  unsigned int* flags = (unsigned int*)take(2048 * sizeof(unsigned int));  // [layer][dir*2+half][32]
  bf16* xs = (bf16*)take(16384ull * 320 * 2);
  bf16* preP = (bf16*)take(16384ull * 4096 * 2);
  bf16* h0 = (bf16*)take(16384ull * 1024 * 2);
  bf16* h1 = (bf16*)take(16384ull * 1024 * 2);
  float* emitb = (float*)take(16384ull * 64 * 4);
  bf16* W0B = (bf16*)take(4096ull * 320 * 2);
  bf16* W1B = (bf16*)take(4096ull * 1024 * 2);
  bf16* WhhB = (bf16*)take(4ull * 1048576 * 2);
  bf16* WoB = (bf16*)take(64ull * 1024 * 2);
  float* bias0 = (float*)take(4096 * 4);
  float* bias1 = (float*)take(4096 * 4);

  hipMemsetAsync(flags, 0, 2048 * sizeof(unsigned int), stream);
  hipLaunchKernelGGL(pack_w0, dim3(5120), dim3(256), 0, stream, Wih0f, Wih0b, W0B);
  hipLaunchKernelGGL(pack_whh, dim3(4096), dim3(256), 0, stream, Whh0f, WhhB + 0ull * 1048576);
  hipLaunchKernelGGL(pack_whh, dim3(4096), dim3(256), 0, stream, Whh0b, WhhB + 1ull * 1048576);
  hipLaunchKernelGGL(pack_whh, dim3(4096), dim3(256), 0, stream, Whh1f, WhhB + 2ull * 1048576);
  hipLaunchKernelGGL(pack_whh, dim3(4096), dim3(256), 0, stream, Whh1b, WhhB + 3ull * 1048576);
  hipLaunchKernelGGL(pack_w1, dim3(16384), dim3(256), 0, stream, Wih1f, Wih1b, W1B);
  hipLaunchKernelGGL(pack_wout, dim3(256), dim3(256), 0, stream, Wout, WoB);
  hipLaunchKernelGGL(pack_bias, dim3(16), dim3(256), 0, stream, b0f, b0b, bias0);
  hipLaunchKernelGGL(pack_bias, dim3(16), dim3(256), 0, stream, b1f, b1b, bias1);
  hipLaunchKernelGGL(embed_k, dim3(20480), dim3(256), 0, stream, x, embed, xs);

  hipLaunchKernelGGL(gemm_nt, dim3(256, 16), dim3(256), 0, stream, xs, W0B, preP, 320, 10);
  {
    const bf16* a0 = preP; const bf16* a1 = WhhB; const float* a2 = bias0; bf16* a3 = h0;
    unsigned int* a4 = flags;  // layer0 flag region
    void* args[] = {&a0, &a1, &a2, &a3, &a4};
    hipLaunchCooperativeKernel((void*)(&lstm_st<1>), dim3(32, 2, 2), dim3(256), args, 0, stream);
  }
  hipLaunchKernelGGL(gemm_nt, dim3(256, 16), dim3(256), 0, stream, h0, W1B, preP, 1024, 32);
  {
    const bf16* a0 = preP; const bf16* a1 = WhhB + 2ull * 1048576; const float* a2 = bias1; bf16* a3 = h1;
    unsigned int* a4 = flags + 1024;  // layer1 flag region
    void* args[] = {&a0, &a1, &a2, &a3, &a4};
    hipLaunchCooperativeKernel((void*)(&lstm_st<0>), dim3(32, 2), dim3(256), args, 0, stream);
  }
  hipLaunchKernelGGL(emit_k, dim3(256), dim3(256), 0, stream, h1, WoB, bout, x, emitb);
  hipLaunchKernelGGL(crf_k, dim3(64), dim3(256), 0, stream, emitb, trans, x, y0, (float*)d_out);
}

// Round 10
// 3117.956 us; speedup vs baseline: 3.4248x; 1.1228x over previous
//
#include <hip/hip_runtime.h>
#include <hip/hip_bf16.h>

typedef short bf16x4 __attribute__((ext_vector_type(4)));
typedef short bf16x8 __attribute__((ext_vector_type(8)));
typedef short bf16x16 __attribute__((ext_vector_type(16)));
typedef float f32x4 __attribute__((ext_vector_type(4)));
typedef __hip_bfloat16 bf16;
typedef unsigned long long ull;

#define NEGV -10000.0f

// Problem dims: B=64, T=256, E=300, H=500, K=64(tags), V=32000
// Padded: Ep=320, Hp=512, layer-1 input 2*Hp=1024, gate width 4096 = 2dir*4gate*512

__device__ __forceinline__ float sigm(float v) { return 1.0f / (1.0f + __expf(-v)); }
__device__ __forceinline__ float tanh_(float v) { float e = __expf(2.0f * v); return 1.0f - 2.0f / (e + 1.0f); }

// async global->LDS, 16B per lane: global src includes per-lane offset, LDS base wave-uniform
__device__ __forceinline__ void async_load16(const bf16* g, const char* l) {
  __builtin_amdgcn_global_load_lds((const __attribute__((address_space(1))) void*)g,
                                   (__attribute__((address_space(3))) void*)l, 16, 0, 0);
}

// ---------------- weight packing into MFMA fragment-linear layout ----------------
// B-frag layout: dst[((nt*Kt + kt)*64 + lane)*8 + u] = B[kt*32 + (lane>>4)*8 + u][nt*16 + (lane&15)]

__global__ __launch_bounds__(256) void pack_w0(const float* __restrict__ wf, const float* __restrict__ wb,
                                               bf16* __restrict__ dst) {
  int idx = blockIdx.x * 256 + threadIdx.x;            // 4096*320 = 1310720
  int u = idx & 7, lane = (idx >> 3) & 63, rem = idx >> 9;
  int kt = rem % 10, nt = rem / 10;
  int n = (nt << 4) + (lane & 15), k = (kt << 5) + ((lane >> 4) << 3) + u;
  int d = n >> 11, g = (n >> 9) & 3, j = n & 511;
  float v = 0.f;
  if (j < 500 && k < 300) v = (d ? wb : wf)[(g * 500 + j) * 300 + k];
  dst[idx] = __float2bfloat16(v);
}

__global__ __launch_bounds__(256) void pack_whh(const float* __restrict__ w, bf16* __restrict__ dst) {
  int idx = blockIdx.x * 256 + threadIdx.x;            // 2048*512 = 1048576
  int u = idx & 7, lane = (idx >> 3) & 63, rem = idx >> 9;
  int kt = rem & 15, nt = rem >> 4;
  int n = (nt << 4) + (lane & 15), k = (kt << 5) + ((lane >> 4) << 3) + u;
  int g = n >> 9, j = n & 511;
  float v = 0.f;
  if (j < 500 && k < 500) v = w[(g * 500 + j) * 500 + k];
  dst[idx] = __float2bfloat16(v);
}

__global__ __launch_bounds__(256) void pack_w1(const float* __restrict__ wf, const float* __restrict__ wb,
                                               bf16* __restrict__ dst) {
  int idx = blockIdx.x * 256 + threadIdx.x;            // 4096*1024 = 4194304
  int u = idx & 7, lane = (idx >> 3) & 63, rem = idx >> 9;
  int kt = rem & 31, nt = rem >> 5;
  int n = (nt << 4) + (lane & 15), k = (kt << 5) + ((lane >> 4) << 3) + u;
  int d = n >> 11, g = (n >> 9) & 3, j = n & 511;
  int kk = k & 511;
  int ks = (k < 512) ? kk : 500 + kk;
  float v = 0.f;
  if (j < 500 && kk < 500) v = (d ? wb : wf)[(g * 500 + j) * 1000 + ks];
  dst[idx] = __float2bfloat16(v);
}

__global__ __launch_bounds__(256) void pack_wout(const float* __restrict__ w, bf16* __restrict__ dst) {
  int idx = blockIdx.x * 256 + threadIdx.x;            // 4*32*512 = 65536
  int u = idx & 7, lane = (idx >> 3) & 63, rem = idx >> 9;
  int kt = rem & 31, nt = rem >> 5;
  int n = (nt << 4) + (lane & 15), k = (kt << 5) + ((lane >> 4) << 3) + u;
  int kk = k & 511;
  int ks = (k < 512) ? kk : 500 + kk;
  float v = 0.f;
  if (kk < 500) v = w[n * 1000 + ks];
  dst[idx] = __float2bfloat16(v);
}

__global__ __launch_bounds__(256) void pack_bias(const float* __restrict__ bf_, const float* __restrict__ bb_,
                                                 float* __restrict__ dst) {
  int idx = blockIdx.x * 256 + threadIdx.x;            // 4096
  int d = idx >> 11, g = (idx >> 9) & 3, j = idx & 511;
  dst[idx] = (j < 500) ? (d ? bb_ : bf_)[g * 500 + j] : 0.f;
}

// ---------------- embedding gather -> bf16 [T*B][320] ----------------
__global__ __launch_bounds__(256) void embed_k(const int* __restrict__ x, const float* __restrict__ em,
                                               bf16* __restrict__ xs) {
  int idx = blockIdx.x * 256 + threadIdx.x;            // 16384*320
  int e = idx % 320;
  int row = idx / 320;
  int t = row >> 6, b = row & 63;
  float v = 0.f;
  if (e < 300) {
    int xv = x[b * 256 + t];
    v = em[(size_t)xv * 300 + e];
  }
  xs[idx] = __float2bfloat16(v);
}

// ---------------- MFMA GEMM: preP = A[16384][Kdim] @ Bfrag, epilogue scatters into
// per-thread-contiguous lstm consumption layout:
// preP[(((t*2+dir)*32+jb)*4+gate)*1024 + lane*16 + (mt*4+r)]
__global__ __launch_bounds__(256) void gemm_nt(const bf16* __restrict__ A, const bf16* __restrict__ Bf,
                                               bf16* __restrict__ C, int Kdim, int Kt) {
  const int lane = threadIdx.x & 63, wave = threadIdx.x >> 6;
  const int lr = lane & 15, lh = lane >> 4;
  const int mb = blockIdx.x * 64;
  const int ntb = blockIdx.y * 16 + wave * 4;
  f32x4 acc[4][4] = {};
  for (int kt = 0; kt < Kt; ++kt) {
    bf16x8 a[4], b[4];
#pragma unroll
    for (int mt = 0; mt < 4; ++mt)
      a[mt] = *(const bf16x8*)(A + (size_t)(mb + mt * 16 + lr) * Kdim + kt * 32 + lh * 8);
#pragma unroll
    for (int q = 0; q < 4; ++q)
      b[q] = *(const bf16x8*)(Bf + ((size_t)(ntb + q) * Kt + kt) * 512 + lane * 8);
#pragma unroll
    for (int mt = 0; mt < 4; ++mt)
#pragma unroll
      for (int q = 0; q < 4; ++q)
        acc[mt][q] = __builtin_amdgcn_mfma_f32_16x16x32_bf16(a[mt], b[q], acc[mt][q], 0, 0, 0);
  }
  const int t = blockIdx.x;  // rows [mb, mb+64) are exactly timestep t
#pragma unroll
  for (int q = 0; q < 4; ++q) {
    const int colbase = (ntb + q) * 16;
    const int dirq = colbase >> 11, gq = (colbase >> 9) & 3, jbq = (colbase >> 4) & 31;
    unsigned short vals[16];
#pragma unroll
    for (int mt = 0; mt < 4; ++mt)
#pragma unroll
      for (int r = 0; r < 4; ++r) {
        bf16 hb = __float2bfloat16(acc[mt][q][r]);
        vals[mt * 4 + r] = *(unsigned short*)&hb;
      }
    bf16* outp = C + ((((size_t)t * 2 + dirq) * 32 + jbq) * 4 + gq) * 1024 + lane * 16;
    *(bf16x8*)(outp) = *(const bf16x8*)(vals);
    *(bf16x8*)(outp + 8) = *(const bf16x8*)(vals + 8);
  }
}

// ---------------- cooperative bidirectional LSTM layer (batch-partitioned) ----------------
// grid(32 jb, 2 dir, NPART parts), NPART = 64/ROWS. Block owns ROWS batch rows of its
// (jb,dir) column tile. Flag group = (dir,part): 32 producers (batch rows never mix).
// h tile staged via global_load_lds into LDS with STRIDE-1040 row pitch: row r at byte
// r*1040 (65 x 16B) shifts bank-slot by 1 per row -> quarter-wave ds_read_b128 hits all
// 8 slots with 2 lanes each = conflict-free (m136: 2-way is free). No XOR anywhere.
// Whh frags reg-resident (LDS-A path protects them from remat - proven R5/R9 vs R6/R8).
template <int ROWS>
__global__ __launch_bounds__(256, 1) void lstm_st(const bf16* __restrict__ preP, const bf16* __restrict__ whh,
                                                  const float* __restrict__ bias, bf16* __restrict__ hout,
                                                  unsigned int* __restrict__ flags) {
  constexpr int MT = ROWS / 16;
  constexpr int NPART = 64 / ROWS;
  const int tid = threadIdx.x, lane = tid & 63, wave = tid >> 6;
  const int lr = lane & 15, lh = lane >> 4;
  const int jb = blockIdx.x, dir = blockIdx.y, part = blockIdx.z;
  unsigned int* flg = flags + (dir * NPART + part) * 64;
  unsigned int* myflg = flg + jb;
  __shared__ __align__(64) char hlds[ROWS * 1040];  // stride-1040 rows
  __shared__ float xch[4 * ROWS * 17];              // [gate][local row][16 cols] pad 17
  __shared__ float cst[ROWS * 16];                  // c-state fp32, persistent
  for (int i = tid; i < ROWS * 16; i += 256) cst[i] = 0.f;
  const float bb = bias[dir * 2048 + wave * 512 + jb * 16 + lr];
  const bf16* wbase = whh + ((size_t)(dir * 128 + wave * 32 + jb) * 16) * 512 + lane * 8;

  // recurrent weights resident in registers (16 frags = 64 VGPRs)
  bf16x8 wfrag[16];
#pragma unroll
  for (int kt = 0; kt < 16; ++kt) wfrag[kt] = *(const bf16x8*)(wbase + kt * 512);

  // packed pre-activations for first step (this part's MT*4 shorts, contiguous)
  unsigned short pf[MT * 4];
  {
    const int t0 = dir ? 255 : 0;
    const bf16* pb = preP + ((((size_t)t0 * 2 + dir) * 32 + jb) * 4 + wave) * 1024 + lane * 16 + part * MT * 4;
    if constexpr (MT == 1) *(bf16x4*)pf = *(const bf16x4*)pb;
    else if constexpr (MT == 2) *(bf16x8*)pf = *(const bf16x8*)pb;
    else *(bf16x16*)pf = *(const bf16x16*)pb;
  }

  for (int s = 0; s < 256; ++s) {
    const int t = dir ? 255 - s : s;
    f32x4 acc[MT] = {};
    if (s > 0) {
      // wait: all 32 producer blocks of this (dir,part) group finished step s-1
      const unsigned int tgt = (unsigned int)s;
      for (;;) {
        unsigned int v = __hip_atomic_load(flg + (lane & 31), __ATOMIC_RELAXED, __HIP_MEMORY_SCOPE_AGENT);
        if (__all((int)(v >= tgt))) break;
      }
      asm volatile("" ::: "memory");
      const int tp = dir ? t + 1 : t - 1;
      const bf16* hp = hout + (size_t)tp * 65536 + dir * 512;
      // async stage: wave w covers local rows i*4+w; plain linear source, stride-1040 LDS
#pragma unroll
      for (int i = 0; i < ROWS / 4; ++i) {
        const int row = i * 4 + wave;  // local row
        async_load16(hp + (size_t)(part * ROWS + row) * 1024 + lane * 8, hlds + row * 1040);
      }
      asm volatile("s_waitcnt vmcnt(0)" ::: "memory");
      __syncthreads();
#pragma unroll 4
      for (int kt = 0; kt < 16; ++kt) {
#pragma unroll
        for (int mt = 0; mt < MT; ++mt) {
          const int row = mt * 16 + lr;
          const bf16x8 afr = *(const bf16x8*)(hlds + row * 1040 + kt * 64 + lh * 16);
          acc[mt] = __builtin_amdgcn_mfma_f32_16x16x32_bf16(afr, wfrag[kt], acc[mt], 0, 0, 0);
        }
      }
    }
#pragma unroll
    for (int mt = 0; mt < MT; ++mt)
#pragma unroll
      for (int r = 0; r < 4; ++r) {
        bf16 pv; *(unsigned short*)&pv = pf[mt * 4 + r];
        xch[(wave * ROWS + mt * 16 + lh * 4 + r) * 17 + lr] = acc[mt][r] + bb + __bfloat162float(pv);
      }
    __syncthreads();
    // cell phase: 2 cells/thread, 4B coherent store; ROWS*8 active threads
    if (tid < ROWS * 8) {
      const int row = tid >> 3, c0 = (tid & 7) * 2;
      unsigned int pk = 0;
#pragma unroll
      for (int i = 0; i < 2; ++i) {
        int col = c0 + i;
        float gi = xch[(0 * ROWS + row) * 17 + col];
        float gf = xch[(1 * ROWS + row) * 17 + col];
        float gg = xch[(2 * ROWS + row) * 17 + col];
        float go = xch[(3 * ROWS + row) * 17 + col];
        float c = cst[row * 16 + col];
        float cn = sigm(gf) * c + sigm(gi) * tanh_(gg);
        cst[row * 16 + col] = cn;
        bf16 hb = __float2bfloat16(sigm(go) * tanh_(cn));
        pk |= (unsigned int)(*(unsigned short*)&hb) << (16 * i);
      }
      unsigned int* hq =
          (unsigned int*)(hout + ((size_t)t * 64 + part * ROWS + row) * 1024 + dir * 512 + jb * 16 + c0);
      __hip_atomic_store(hq, pk, __ATOMIC_RELAXED, __HIP_MEMORY_SCOPE_AGENT);
    }
    // release: drain write-through stores, join waves, publish epoch
    asm volatile("s_waitcnt vmcnt(0)" ::: "memory");
    __syncthreads();
    if (tid == 0)
      __hip_atomic_store(myflg, (unsigned int)(s + 1), __ATOMIC_RELAXED, __HIP_MEMORY_SCOPE_AGENT);
    // prefetch next step's packed pre (hides under the next poll)
    if (s < 255) {
      const int tn = dir ? t - 1 : t + 1;
      const bf16* pb = preP + ((((size_t)tn * 2 + dir) * 32 + jb) * 4 + wave) * 1024 + lane * 16 + part * MT * 4;
      if constexpr (MT == 1) *(bf16x4*)pf = *(const bf16x4*)pb;
      else if constexpr (MT == 2) *(bf16x8*)pf = *(const bf16x8*)pb;
      else *(bf16x16*)pf = *(const bf16x16*)pb;
    }
  }
}

// ---------------- emit projection: emit[16384][64] = h1 @ WoutB + bout, masked ----------------
__global__ __launch_bounds__(256) void emit_k(const bf16* __restrict__ h1, const bf16* __restrict__ wo,
                                              const float* __restrict__ bout, const int* __restrict__ x,
                                              float* __restrict__ emit) {
  const int tid = threadIdx.x, lane = tid & 63, wave = tid >> 6;
  const int lr = lane & 15, lh = lane >> 4;
  const int mb = blockIdx.x * 64 + wave * 16;
  f32x4 acc[4] = {};
  for (int kt = 0; kt < 32; ++kt) {
    bf16x8 a = *(const bf16x8*)(h1 + (size_t)(mb + lr) * 1024 + kt * 32 + lh * 8);
#pragma unroll
    for (int q = 0; q < 4; ++q) {
      bf16x8 b = *(const bf16x8*)(wo + ((size_t)(q * 32 + kt) * 64 + lane) * 8);
      acc[q] = __builtin_amdgcn_mfma_f32_16x16x32_bf16(a, b, acc[q], 0, 0, 0);
    }
  }
#pragma unroll
  for (int q = 0; q < 4; ++q)
#pragma unroll
    for (int r = 0; r < 4; ++r) {
      int row = mb + lh * 4 + r;
      int col = q * 16 + lr;
      int tt = row >> 6, bi = row & 63;
      float m = (x[bi * 256 + tt] > 0) ? 1.f : 0.f;
      emit[(size_t)row * 64 + col] = (acc[q][r] + bout[col]) * m;
    }
}

// ---------------- CRF forward + gold score, one block per batch element ----------------
__global__ __launch_bounds__(256) void crf_k(const float* __restrict__ emit, const float* __restrict__ trans,
                                             const int* __restrict__ x, const int* __restrict__ y0,
                                             float* __restrict__ out) {
  const int b = blockIdx.x, tid = threadIdx.x;
  __shared__ float tr[4096];
  __shared__ float sc[2][64];
  __shared__ float pm[4][64], ps[4][64];
  __shared__ float redw[4];
  for (int i = tid; i < 4096; i += 256) tr[i] = trans[i];
  if (tid < 64) sc[0][tid] = (tid == 2) ? 0.f : NEGV;  // SOS=2
  __syncthreads();
  {
    const int t = tid;
    const int tag = y0[b * 256 + t];
    const int prev = t ? y0[b * 256 + t - 1] : 2;
    const float m = (x[b * 256 + t] > 0) ? 1.f : 0.f;
    float g = emit[((size_t)t * 64 + b) * 64 + tag] + tr[tag * 64 + prev] * m;
    for (int o = 32; o; o >>= 1) g += __shfl_down(g, o, 64);
    if ((tid & 63) == 0) redw[tid >> 6] = g;
  }
  __syncthreads();
  const float gold = redw[0] + redw[1] + redw[2] + redw[3];
  const int j = tid & 63, kq = tid >> 6;
  int cur = 0;
  for (int t = 0; t < 256; ++t) {
    const float* trj = tr + j * 64 + kq * 16;
    const float* scc = sc[cur] + kq * 16;
    float v[16];
    float mx = -3.0e38f;
#pragma unroll
    for (int k = 0; k < 16; ++k) {
      v[k] = scc[k] + trj[k];
      mx = fmaxf(mx, v[k]);
    }
    float sm = 0.f;
#pragma unroll
    for (int k = 0; k < 16; ++k) sm += __expf(v[k] - mx);
    pm[kq][j] = mx;
    ps[kq][j] = sm;
    __syncthreads();
    if (kq == 0) {
      float M = fmaxf(fmaxf(pm[0][j], pm[1][j]), fmaxf(pm[2][j], pm[3][j]));
      float S = ps[0][j] * __expf(pm[0][j] - M) + ps[1][j] * __expf(pm[1][j] - M) +
                ps[2][j] * __expf(pm[2][j] - M) + ps[3][j] * __expf(pm[3][j] - M);
      float nv = M + __logf(S) + emit[((size_t)t * 64 + b) * 64 + j];
      sc[cur ^ 1][j] = (x[b * 256 + t] > 0) ? nv : sc[cur][j];
    }
    __syncthreads();
    cur ^= 1;
  }
  if (tid < 64) {
    float v2 = sc[cur][tid];
    float M = v2;
    for (int o = 32; o; o >>= 1) M = fmaxf(M, __shfl_xor(M, o, 64));
    float s2 = __expf(v2 - M);
    for (int o = 32; o; o >>= 1) s2 += __shfl_xor(s2, o, 64);
    if (tid == 0) out[b] = M + __logf(s2) - gold;
  }
}

// ---------------- launch ----------------
extern "C" void kernel_launch(void* const* d_in, const int* in_sizes, int n_in, void* d_out, int out_size,
                              void* d_ws, size_t ws_size, hipStream_t stream) {
  (void)in_sizes; (void)n_in; (void)out_size; (void)ws_size;
  const int* x = (const int*)d_in[0];
  const int* y0 = (const int*)d_in[1];
  const float* embed = (const float*)d_in[2];
  const float* Wih0f = (const float*)d_in[3];
  const float* Whh0f = (const float*)d_in[4];
  const float* b0f = (const float*)d_in[5];
  const float* Wih0b = (const float*)d_in[6];
  const float* Whh0b = (const float*)d_in[7];
  const float* b0b = (const float*)d_in[8];
  const float* Wih1f = (const float*)d_in[9];
  const float* Whh1f = (const float*)d_in[10];
  const float* b1f = (const float*)d_in[11];
  const float* Wih1b = (const float*)d_in[12];
  const float* Whh1b = (const float*)d_in[13];
  const float* b1b = (const float*)d_in[14];
  const float* Wout = (const float*)d_in[15];
  const float* bout = (const float*)d_in[16];
  const float* trans = (const float*)d_in[17];

  char* p = (char*)d_ws;
  auto take = [&](size_t n) { char* r = p; p += (n + 255) & ~(size_t)255; return r; };
  unsigned int* flags = (unsigned int*)take(2048 * sizeof(unsigned int));  // [layer][dir*NPART+part][32]
  bf16* xs = (bf16*)take(16384ull * 320 * 2);
  bf16* preP = (bf16*)take(16384ull * 4096 * 2);
  bf16* h0 = (bf16*)take(16384ull * 1024 * 2);
  bf16* h1 = (bf16*)take(16384ull * 1024 * 2);
  float* emitb = (float*)take(16384ull * 64 * 4);
  bf16* W0B = (bf16*)take(4096ull * 320 * 2);
  bf16* W1B = (bf16*)take(4096ull * 1024 * 2);
  bf16* WhhB = (bf16*)take(4ull * 1048576 * 2);
  bf16* WoB = (bf16*)take(64ull * 1024 * 2);
  float* bias0 = (float*)take(4096 * 4);
  float* bias1 = (float*)take(4096 * 4);

  hipMemsetAsync(flags, 0, 2048 * sizeof(unsigned int), stream);
  hipLaunchKernelGGL(pack_w0, dim3(5120), dim3(256), 0, stream, Wih0f, Wih0b, W0B);
  hipLaunchKernelGGL(pack_whh, dim3(4096), dim3(256), 0, stream, Whh0f, WhhB + 0ull * 1048576);
  hipLaunchKernelGGL(pack_whh, dim3(4096), dim3(256), 0, stream, Whh0b, WhhB + 1ull * 1048576);
  hipLaunchKernelGGL(pack_whh, dim3(4096), dim3(256), 0, stream, Whh1f, WhhB + 2ull * 1048576);
  hipLaunchKernelGGL(pack_whh, dim3(4096), dim3(256), 0, stream, Whh1b, WhhB + 3ull * 1048576);
  hipLaunchKernelGGL(pack_w1, dim3(16384), dim3(256), 0, stream, Wih1f, Wih1b, W1B);
  hipLaunchKernelGGL(pack_wout, dim3(256), dim3(256), 0, stream, Wout, WoB);
  hipLaunchKernelGGL(pack_bias, dim3(16), dim3(256), 0, stream, b0f, b0b, bias0);
  hipLaunchKernelGGL(pack_bias, dim3(16), dim3(256), 0, stream, b1f, b1b, bias1);
  hipLaunchKernelGGL(embed_k, dim3(20480), dim3(256), 0, stream, x, embed, xs);

  hipLaunchKernelGGL(gemm_nt, dim3(256, 16), dim3(256), 0, stream, xs, W0B, preP, 320, 10);
  {
    const bf16* a0 = preP; const bf16* a1 = WhhB; const float* a2 = bias0; bf16* a3 = h0;
    unsigned int* a4 = flags;  // layer0: quarter-split (16 rows/block)
    void* args[] = {&a0, &a1, &a2, &a3, &a4};
    hipLaunchCooperativeKernel((void*)(&lstm_st<16>), dim3(32, 2, 4), dim3(256), args, 0, stream);
  }
  hipLaunchKernelGGL(gemm_nt, dim3(256, 16), dim3(256), 0, stream, h0, W1B, preP, 1024, 32);
  {
    const bf16* a0 = preP; const bf16* a1 = WhhB + 2ull * 1048576; const float* a2 = bias1; bf16* a3 = h1;
    unsigned int* a4 = flags + 1024;  // layer1: half-split (32 rows/block)
    void* args[] = {&a0, &a1, &a2, &a3, &a4};
    hipLaunchCooperativeKernel((void*)(&lstm_st<32>), dim3(32, 2, 2), dim3(256), args, 0, stream);
  }
  hipLaunchKernelGGL(emit_k, dim3(256), dim3(256), 0, stream, h1, WoB, bout, x, emitb);
  hipLaunchKernelGGL(crf_k, dim3(64), dim3(256), 0, stream, emitb, trans, x, y0, (float*)d_out);
}